// Round 10
// baseline (284.603 us; speedup 1.0000x reference)
//
#include <hip/hip_runtime.h>
#include <math.h>

#define Bb 512
#define Tt 512
#define Kk 128
#define NSTART 126   // K-2
#define NSTOP  127   // K-1

static constexpr float LOG2E = 1.4426950408889634f;
static constexpr float LN2   = 0.6931471805599453f;

__device__ __forceinline__ float fexp2(float x){ return __builtin_amdgcn_exp2f(x); }
__device__ __forceinline__ float flog2(float x){ return __builtin_amdgcn_logf(x); }
__device__ __forceinline__ float frcp (float x){ return __builtin_amdgcn_rcpf(x); }

// acc += e.lo*s.lo + e.hi*s.hi   (packed fp16, fp32 accum; s is an SGPR broadcast)
__device__ __forceinline__ void dot2a(float& acc, unsigned int e, int s){
  asm("v_dot2_f32_f16 %0, %1, %2, %0" : "+v"(acc) : "v"(e), "s"(s));
}
// pack two f32 -> packed f16 {lo, hi} with ROUND-TO-NEAREST-EVEN
__device__ __forceinline__ unsigned int pk2f16_rne(float lo, float hi){
  unsigned int ulo, uhi, r;
  asm("v_cvt_f16_f32 %0, %1" : "=v"(ulo) : "v"(lo));
  asm("v_cvt_f16_f32 %0, %1" : "=v"(uhi) : "v"(hi));
  asm("v_pack_b32_f16 %0, %1, %2" : "=v"(r) : "v"(ulo), "v"(uhi));
  return r;
}
__device__ __forceinline__ float cvt_f32_f16(unsigned int u){
  float f; asm("v_cvt_f32_f16 %0, %1" : "=v"(f) : "v"(u)); return f;
}

template<int CTRL>
__device__ __forceinline__ float dpp_mov(float s){
  union {float f; int i;} a, r; a.f = s;
  r.i = __builtin_amdgcn_update_dpp(a.i, a.i, CTRL, 0xf, 0xf, false);
  return r.f;
}
#define QP_XOR1  0xB1    // quad_perm [1,0,3,2]
#define QP_XOR2  0x4E    // quad_perm [2,3,0,1]
#define ROW_ROR4 0x124   // row_ror:4
#define ROW_ROR8 0x128   // row_ror:8

__device__ __forceinline__ float rlanef(float x, int lane){
  union {float f; int i;} v; v.f = x;
  union {int i; float f;} r; r.i = __builtin_amdgcn_readlane(v.i, lane);
  return r.f;
}

// ---- one CRF chain per 64-lane wave; no LDS, no barriers, no DS in loop ----
// Lane l owns next-states {2l, 2l+1}; alpha (128 fp16) = one dword per lane.
// Per step each lane's alpha dword is readlane-broadcast (SGPR) into
// v_dot2_f32_f16 against E rows held as packed fp16 in 128 VGPRs.
// amdgpu_waves_per_eu(1,1): full 512-reg budget -> no AGPR stash of E.
// Renorm wave max -> 2048 every step (fp16 subnormal cutoff e^-17 rel;
// one-step growth <= ~2e9 held in fp32). RNE for all f32->f16 conversions.
__global__ __attribute__((amdgpu_flat_work_group_size(64, 64),
                          amdgpu_waves_per_eu(1, 1))) void crf_rl2(
    const float* __restrict__ feats,   // [B,T,K]
    const int*   __restrict__ tags,    // [B,T]
    const float* __restrict__ trans,   // [K,K]  trans[next, prev]
    float* __restrict__ part)          // [B]
{
  const int b = blockIdx.x;
  const int l = threadIdx.x;   // 0..63

  // ---- E rows 2l, 2l+1 as packed fp16 pairs along prev: 128 VGPRs ----
  unsigned int E0[64], E1[64];
  {
    const float* t0 = trans + (size_t)(2*l)     * Kk;
    const float* t1 = trans + (size_t)(2*l + 1) * Kk;
    #pragma unroll
    for (int j = 0; j < 64; ++j) {
      float2 v0 = *(const float2*)(t0 + 2*j);
      float2 v1 = *(const float2*)(t1 + 2*j);
      E0[j] = pk2f16_rne(fexp2(v0.x * LOG2E), fexp2(v0.y * LOG2E));
      E1[j] = pk2f16_rne(fexp2(v1.x * LOG2E), fexp2(v1.y * LOG2E));
    }
  }
  #pragma unroll
  for (int j = 0; j < 64; ++j)
    asm volatile("" : "+v"(E0[j]), "+v"(E1[j]));

  // alpha0: state 126 = 2048.0 (lane 63 lo half), else 0; C2 starts at -11
  unsigned int a = (l == 63) ? 0x00006800u : 0u;   // fp16 2048 in low half
  float C2 = -11.0f;                               // renorm offset, log2 units

  const float* fp2 = feats + (size_t)b * Tt * Kk + 2*l;  // this lane's 2 states
  float2 F[4];
  #pragma unroll
  for (int i = 0; i < 4; ++i) F[i] = *(const float2*)(fp2 + (size_t)i * Kk);

  for (int t = 0; t < Tt; t += 4) {
    #pragma unroll
    for (int u = 0; u < 4; ++u) {
      const float f0 = F[u].x, f1 = F[u].y;
      {  // refill ring slot for step t+4+u (clamped; harmless re-read at tail)
        int tn = t + 4 + u; if (tn > Tt - 1) tn = Tt - 1;
        F[u] = *(const float2*)(fp2 + (size_t)tn * Kk);
      }

      float A0=0.f,A1=0.f,A2=0.f,A3=0.f, B0=0.f,B1=0.f,B2=0.f,B3=0.f;
      #pragma unroll
      for (int i = 0; i < 64; i += 8) {
        // batch 8 readlanes first: buries the SGPR-write -> VALU-read hazard
        const int s0 = __builtin_amdgcn_readlane((int)a, i+0);
        const int s1 = __builtin_amdgcn_readlane((int)a, i+1);
        const int s2 = __builtin_amdgcn_readlane((int)a, i+2);
        const int s3 = __builtin_amdgcn_readlane((int)a, i+3);
        const int s4 = __builtin_amdgcn_readlane((int)a, i+4);
        const int s5 = __builtin_amdgcn_readlane((int)a, i+5);
        const int s6 = __builtin_amdgcn_readlane((int)a, i+6);
        const int s7 = __builtin_amdgcn_readlane((int)a, i+7);
        dot2a(A0, E0[i+0], s0);  dot2a(B0, E1[i+0], s0);
        dot2a(A1, E0[i+1], s1);  dot2a(B1, E1[i+1], s1);
        dot2a(A2, E0[i+2], s2);  dot2a(B2, E1[i+2], s2);
        dot2a(A3, E0[i+3], s3);  dot2a(B3, E1[i+3], s3);
        dot2a(A0, E0[i+4], s4);  dot2a(B0, E1[i+4], s4);
        dot2a(A1, E0[i+5], s5);  dot2a(B1, E1[i+5], s5);
        dot2a(A2, E0[i+6], s6);  dot2a(B2, E1[i+6], s6);
        dot2a(A3, E0[i+7], s7);  dot2a(B3, E1[i+7], s7);
      }
      const float sA = (A0 + A1) + (A2 + A3);
      const float sB = (B0 + B1) + (B2 + B3);
      float y0 = fexp2(f0 * LOG2E) * sA;
      float y1 = fexp2(f1 * LOG2E) * sB;

      // ---- wave max -> renorm to 2048, pure VALU (DPP) + readlane ----
      float m = fmaxf(y0, y1);
      m = fmaxf(m, dpp_mov<QP_XOR1>(m));
      m = fmaxf(m, dpp_mov<QP_XOR2>(m));
      m = fmaxf(m, dpp_mov<ROW_ROR4>(m));
      m = fmaxf(m, dpp_mov<ROW_ROR8>(m));   // 16-lane row max in all lanes
      const float mm = fmaxf(fmaxf(rlanef(m, 0),  rlanef(m, 16)),
                             fmaxf(rlanef(m, 32), rlanef(m, 48)));
      C2 += flog2(mm) - 11.0f;
      const float inv = frcp(mm) * 2048.0f;
      a = pk2f16_rne(y0 * inv, y1 * inv);
    }
  }

  // ---- forward score: ln( sum_n a[n] * exp(T[STOP,n]) ) + offset ----
  {
    const float a0 = cvt_f32_f16(a);
    const float a1 = cvt_f32_f16(a >> 16);
    const float e0 = fexp2(trans[(size_t)NSTOP * Kk + 2*l]     * LOG2E);
    const float e1 = fexp2(trans[(size_t)NSTOP * Kk + 2*l + 1] * LOG2E);
    float v = a0 * e0 + a1 * e1;
    #pragma unroll
    for (int off = 32; off >= 1; off >>= 1) v += __shfl_xor(v, off, 64);
    const float fwd = LN2 * (C2 + flog2(v));

    // ---- gold path score (8 timesteps per lane; exact fp32) ----
    const int* tg = tags + (size_t)b * Tt;
    const float* fbase = feats + (size_t)b * Tt * Kk;
    float g = 0.0f;
    #pragma unroll
    for (int k2 = 0; k2 < Tt / 64; ++k2) {
      const int tt   = l + 64 * k2;
      const int curt = tg[tt];
      const int prv  = (tt == 0) ? NSTART : tg[tt - 1];
      g += trans[(size_t)curt * Kk + prv] + fbase[(size_t)tt * Kk + curt];
    }
    if (l == 0) g += trans[(size_t)NSTOP * Kk + tg[Tt - 1]];
    #pragma unroll
    for (int off = 32; off >= 1; off >>= 1) g += __shfl_xor(g, off, 64);

    if (l == 0) part[b] = fwd - g;
  }
}

__global__ __launch_bounds__(256) void reduce_mean_kernel(
    const float* __restrict__ part, float* __restrict__ out)
{
  __shared__ float buf[4];
  const int tid = threadIdx.x;
  float v = part[tid] + part[tid + 256];
  #pragma unroll
  for (int off = 32; off >= 1; off >>= 1) v += __shfl_xor(v, off, 64);
  if ((tid & 63) == 0) buf[tid >> 6] = v;
  __syncthreads();
  if (tid == 0)
    out[0] = (buf[0] + buf[1] + buf[2] + buf[3]) * (1.0f / (float)Bb);
}

extern "C" void kernel_launch(void* const* d_in, const int* in_sizes, int n_in,
                              void* d_out, int out_size, void* d_ws, size_t ws_size,
                              hipStream_t stream) {
  const float* feats = (const float*)d_in[0];
  const int*   tags  = (const int*)d_in[1];
  const float* trans = (const float*)d_in[2];
  float* part = (float*)d_ws;

  crf_rl2<<<dim3(Bb), dim3(64), 0, stream>>>(feats, tags, trans, part);
  reduce_mean_kernel<<<dim3(1), dim3(256), 0, stream>>>(part, (float*)d_out);
}